// Round 11
// baseline (68538.019 us; speedup 1.0000x reference)
//
#include <hip/hip_runtime.h>
#include <cstdint>
#include <cstddef>

#define DEV __device__ __forceinline__

// Problem constants
constexpr int V  = 96103;
constexpr int VPAD = 96104;   // 16B-aligned logits row stride
constexpr int D  = 1024;
constexpr int H  = 16;
constexpr int DH = 64;
constexpr int F  = 4096;
constexpr int NL = 2;
constexpr int S  = 512;
constexpr int T  = 80;
constexpr int B  = 4;
constexpr int NS = 5;
constexpr int BN = 20;
constexpr int KTOP = 100;
constexpr int EOS = 1;
constexpr int L5C = 128;                       // cols per logits block
constexpr int L5GRID = (V + L5C - 1) / L5C;    // 751

// ---------------------------------------------------------------- utilities

DEV float gelu_f(float x) {
  float x3 = x * x * x;
  float inner = 0.7978845608028654f * (x + 0.044715f * x3);
  float tt = tanhf(inner);
  return x * (0.5f * (1.0f + tt));
}

DEV void tf2x32(unsigned k0, unsigned k1, unsigned& x0, unsigned& x1) {
  unsigned ks2 = k0 ^ k1 ^ 0x1BD11BDAu;
#define TFR(rr) { x0 += x1; x1 = (x1 << rr) | (x1 >> (32 - rr)); x1 ^= x0; }
  x0 += k0; x1 += k1;
  TFR(13) TFR(15) TFR(26) TFR(6)
  x0 += k1;  x1 += ks2 + 1u;
  TFR(17) TFR(29) TFR(16) TFR(24)
  x0 += ks2; x1 += k0 + 2u;
  TFR(13) TFR(15) TFR(26) TFR(6)
  x0 += k0;  x1 += k1 + 3u;
  TFR(17) TFR(29) TFR(16) TFR(24)
  x0 += k1;  x1 += ks2 + 4u;
  TFR(13) TFR(15) TFR(26) TFR(6)
  x0 += ks2; x1 += k0 + 5u;
#undef TFR
}

DEV unsigned long long sort_key(float v, unsigned idx) {
  unsigned bb = __float_as_uint(v);
  bb = (bb & 0x80000000u) ? ~bb : (bb | 0x80000000u);
  return ((unsigned long long)bb << 32) | (unsigned long long)(0xFFFFFFFFu - idx);
}

// stage one x-row into LDS + compute LN stats. 256 thr.
DEV void row_ln_stats(const float* __restrict__ xd, int bn, float* xrow,
                      float* wred, float& rstd, float& bco, int tid) {
  int w = tid >> 6, lane = tid & 63;
  float4 v = *(const float4*)(xd + (size_t)bn * D + w * 256 + lane * 4);
  *(float4*)(xrow + w * 256 + lane * 4) = v;
  float s = v.x + v.y + v.z + v.w;
#pragma unroll
  for (int o = 32; o > 0; o >>= 1) s += __shfl_xor(s, o);
  if (lane == 0) wred[w] = s;
  __syncthreads();
  float mean = (wred[0] + wred[1] + wred[2] + wred[3]) * (1.0f / 1024.0f);
  float a = v.x - mean, b = v.y - mean, c = v.z - mean, d = v.w - mean;
  float s2 = a * a + b * b + c * c + d * d;
#pragma unroll
  for (int o = 32; o > 0; o >>= 1) s2 += __shfl_xor(s2, o);
  if (lane == 0) wred[4 + w] = s2;
  __syncthreads();
  rstd = 1.0f / sqrtf((wred[4] + wred[5] + wred[6] + wred[7]) * (1.0f / 1024.0f) + 1e-5f);
  bco = -mean * rstd;
}

// ---------------------------------------------------------------- embeddings

__global__ __launch_bounds__(256) void embed_enc(const int* __restrict__ ids,
                                                 const float* __restrict__ E,
                                                 const float* __restrict__ pos_e,
                                                 float* __restrict__ xe) {
  int row = blockIdx.x;
  int id = ids[row];
  const float* er = E + (size_t)id * D;
  const float* pr = pos_e + (size_t)(row % S) * D;
  float* xr = xe + (size_t)row * D;
  for (int j = threadIdx.x; j < D; j += 256)
    xr[j] = er[j] * 32.0f + pr[j];
}

__global__ __launch_bounds__(256) void embed_dec(const float* __restrict__ E,
                                                 const float* __restrict__ pos_d,
                                                 const int* __restrict__ toks,
                                                 float* __restrict__ xd, int t) {
  int bn = blockIdx.x;
  int prev = (t == 0) ? 0 : toks[bn * T + (t - 1)];
  const float* er = E + (size_t)prev * D;
  const float* pr = pos_d + (size_t)t * D;
  float* xr = xd + (size_t)bn * D;
  for (int j = threadIdx.x; j < D; j += 256)
    xr[j] = er[j] * 32.0f + pr[j];
}

// ---------------------------------------------------------------- layernorm (encoder)

__global__ __launch_bounds__(256) void ln_kernel(const float* __restrict__ x,
                                                 float* __restrict__ y) {
  __shared__ float red[256];
  __shared__ float sv[2];
  int tid = threadIdx.x;
  const float* xr = x + (size_t)blockIdx.x * D;
  float4 v = *(const float4*)(xr + tid * 4);
  red[tid] = v.x + v.y + v.z + v.w;
  __syncthreads();
  for (int k = 128; k > 0; k >>= 1) { if (tid < k) red[tid] += red[tid + k]; __syncthreads(); }
  if (tid == 0) sv[0] = red[0] * (1.0f / 1024.0f);
  __syncthreads();
  float m = sv[0];
  float dx = v.x - m, dy = v.y - m, dz = v.z - m, dw = v.w - m;
  red[tid] = dx * dx + dy * dy + dz * dz + dw * dw;
  __syncthreads();
  for (int k = 128; k > 0; k >>= 1) { if (tid < k) red[tid] += red[tid + k]; __syncthreads(); }
  if (tid == 0) sv[1] = 1.0f / sqrtf(red[0] * (1.0f / 1024.0f) + 1e-5f);
  __syncthreads();
  float r = sv[1];
  float* yr = y + (size_t)blockIdx.x * D;
  float4 o; o.x = dx * r; o.y = dy * r; o.z = dz * r; o.w = dw * r;
  *(float4*)(yr + tid * 4) = o;
}

// ---------------------------------------------------------------- encoder GEMM 128x128

template<int EPI>
__global__ __launch_bounds__(256) void gemm128(const float* __restrict__ A,
                                               const float* __restrict__ W,
                                               const float* X, float* C,
                                               int Kd, int Nd) {
  __shared__ __align__(16) float As[8][128];
  __shared__ __align__(16) float Bs[8][128];
  int tid = threadIdx.x;
  int n0 = blockIdx.x * 128, m0 = blockIdx.y * 128;
  int tx = tid & 15, ty = tid >> 4;
  int ar = tid >> 1, ac = (tid & 1) * 4;
  int br = tid >> 5, bc = (tid & 31) * 4;
  float acc[8][8] = {};
  for (int k0 = 0; k0 < Kd; k0 += 8) {
    float4 av = *(const float4*)(A + (size_t)(m0 + ar) * Kd + k0 + ac);
    float4 wv = *(const float4*)(W + (size_t)(k0 + br) * Nd + n0 + bc);
    __syncthreads();
    As[ac + 0][ar] = av.x; As[ac + 1][ar] = av.y;
    As[ac + 2][ar] = av.z; As[ac + 3][ar] = av.w;
    *(float4*)&Bs[br][bc] = wv;
    __syncthreads();
#pragma unroll
    for (int k = 0; k < 8; ++k) {
      float a8[8], b8[8];
      *(float4*)&a8[0] = *(const float4*)&As[k][ty * 8];
      *(float4*)&a8[4] = *(const float4*)&As[k][ty * 8 + 4];
      *(float4*)&b8[0] = *(const float4*)&Bs[k][tx * 8];
      *(float4*)&b8[4] = *(const float4*)&Bs[k][tx * 8 + 4];
#pragma unroll
      for (int i = 0; i < 8; ++i)
#pragma unroll
        for (int j = 0; j < 8; ++j)
          acc[i][j] = fmaf(a8[i], b8[j], acc[i][j]);
    }
  }
#pragma unroll
  for (int i = 0; i < 8; ++i) {
    int m = m0 + ty * 8 + i;
#pragma unroll
    for (int j = 0; j < 8; ++j) {
      int n = n0 + tx * 8 + j;
      float r = acc[i][j];
      size_t off = (size_t)m * Nd + n;
      if (EPI == 1) r = X[off] + r;
      if (EPI == 2) r = gelu_f(r);
      C[off] = r;
    }
  }
}

// ---------------------------------------------------------------- encoder attention

__global__ __launch_bounds__(256) void enc_attn(const float* __restrict__ qkv,
                                                const int* __restrict__ mask,
                                                float* __restrict__ ab) {
  __shared__ __align__(16) float qv[64];
  __shared__ float sc[512];
  __shared__ float red[256];
  __shared__ float sv[2];
  int tid = threadIdx.x;
  int q = blockIdx.x % S;
  int h = (blockIdx.x / S) % H;
  int b = blockIdx.x / (S * H);
  const float* qrow = qkv + (size_t)(b * S + q) * (3 * D) + h * 64;
  if (tid < 64) qv[tid] = qrow[tid];
  __syncthreads();
  float lmax = -INFINITY;
  for (int k = tid; k < S; k += 256) {
    const float* kr = qkv + (size_t)(b * S + k) * (3 * D) + D + h * 64;
    float dot = 0.0f;
#pragma unroll
    for (int d4 = 0; d4 < 16; ++d4) {
      float4 kk = *(const float4*)(kr + d4 * 4);
      float4 qq = *(const float4*)(qv + d4 * 4);
      dot += qq.x * kk.x + qq.y * kk.y + qq.z * kk.z + qq.w * kk.w;
    }
    float bias = (1.0f - (float)mask[b * S + k]) * -1e9f;
    float val = dot * 0.125f + bias;
    sc[k] = val;
    lmax = fmaxf(lmax, val);
  }
  red[tid] = lmax; __syncthreads();
  for (int k = 128; k > 0; k >>= 1) { if (tid < k) red[tid] = fmaxf(red[tid], red[tid + k]); __syncthreads(); }
  if (tid == 0) sv[0] = red[0];
  __syncthreads();
  float mx = sv[0];
  float lsum = 0.0f;
  for (int k = tid; k < S; k += 256) { float e = expf(sc[k] - mx); sc[k] = e; lsum += e; }
  red[tid] = lsum; __syncthreads();
  for (int k = 128; k > 0; k >>= 1) { if (tid < k) red[tid] += red[tid + k]; __syncthreads(); }
  if (tid == 0) sv[1] = red[0];
  __syncthreads();
  float den = sv[1];
  for (int k = tid; k < S; k += 256) sc[k] = sc[k] / den;
  __syncthreads();
  int d = tid & 63, c = tid >> 6;
  const float* vb = qkv + (size_t)(b * S) * (3 * D) + 2 * D + h * 64 + d;
  float part = 0.0f;
  for (int k = c * 128; k < c * 128 + 128; ++k)
    part = fmaf(sc[k], vb[(size_t)k * (3 * D)], part);
  red[tid] = part; __syncthreads();
  if (tid < 64) {
    float o = red[tid] + red[tid + 64] + red[tid + 128] + red[tid + 192];
    ab[(size_t)(b * S + q) * D + h * 64 + tid] = o;
  }
}

// ---------------------------------------------------------------- fused decode GEMM (r3-proven)

template<int CT, int EPI, bool KV, bool LNIN>
__global__ __launch_bounds__(512) void dec_gemm(const float* __restrict__ x,
                                                const float* __restrict__ W,
                                                const float* Xres, float* Cout,
                                                float* __restrict__ cacheK,
                                                float* __restrict__ cacheV,
                                                int Kd, int Nd, int t, int l) {
  constexpr int KSP = 512 / CT;
  __shared__ float red[CT * 20 * (KSP + 1)];
  __shared__ float redw[CT * (KSP + 1)];
  __shared__ float sab[40];
  int tid = threadIdx.x;
  if constexpr (LNIN) {
    int w = tid >> 6, lane = tid & 63;
    for (int m = w; m < BN; m += 8) {
      const float* xr = x + (size_t)m * 1024 + lane * 16;
      float4 v[4];
      float sum = 0.0f;
#pragma unroll
      for (int j = 0; j < 4; ++j) {
        v[j] = *(const float4*)(xr + j * 4);
        sum += v[j].x + v[j].y + v[j].z + v[j].w;
      }
#pragma unroll
      for (int o = 32; o > 0; o >>= 1) sum += __shfl_xor(sum, o);
      float mean = sum * (1.0f / 1024.0f);
      float vs = 0.0f;
#pragma unroll
      for (int j = 0; j < 4; ++j) {
        float a = v[j].x - mean, b = v[j].y - mean, c2 = v[j].z - mean, d = v[j].w - mean;
        vs += a * a + b * b + c2 * c2 + d * d;
      }
#pragma unroll
      for (int o = 32; o > 0; o >>= 1) vs += __shfl_xor(vs, o);
      float rstd = 1.0f / sqrtf(vs * (1.0f / 1024.0f) + 1e-5f);
      if (lane == 0) { sab[m] = rstd; sab[20 + m] = -mean * rstd; }
    }
    __syncthreads();
  }
  int c = tid % CT, ks = tid / CT;
  int klen = Kd / KSP;
  const float* Wp = W + (size_t)(ks * klen) * Nd + blockIdx.x * CT + c;
  float acc[20] = {};
  float accw = 0.0f;
  for (int kk = 0; kk < klen; kk += 8) {
    float wv[8];
#pragma unroll
    for (int u = 0; u < 8; ++u) wv[u] = Wp[(size_t)u * Nd];
    Wp += (size_t)8 * Nd;
    if constexpr (LNIN)
      accw += wv[0] + wv[1] + wv[2] + wv[3] + wv[4] + wv[5] + wv[6] + wv[7];
    int kb = ks * klen + kk;
#pragma unroll
    for (int m = 0; m < 20; ++m) {
      float4 x0 = *(const float4*)(x + (size_t)m * Kd + kb);
      float4 x1 = *(const float4*)(x + (size_t)m * Kd + kb + 4);
      float a = acc[m];
      a = fmaf(x0.x, wv[0], a); a = fmaf(x0.y, wv[1], a);
      a = fmaf(x0.z, wv[2], a); a = fmaf(x0.w, wv[3], a);
      a = fmaf(x1.x, wv[4], a); a = fmaf(x1.y, wv[5], a);
      a = fmaf(x1.z, wv[6], a); a = fmaf(x1.w, wv[7], a);
      acc[m] = a;
    }
  }
#pragma unroll
  for (int m = 0; m < 20; ++m) red[(c * 20 + m) * (KSP + 1) + ks] = acc[m];
  if constexpr (LNIN) redw[c * (KSP + 1) + ks] = accw;
  __syncthreads();
  if (tid < CT * 20) {
    int cc = tid % CT, m = tid / CT;
    const float* rp = red + (cc * 20 + m) * (KSP + 1);
    float s = 0.0f;
#pragma unroll
    for (int k2 = 0; k2 < KSP; ++k2) s += rp[k2];
    if constexpr (LNIN) {
      const float* rw = redw + cc * (KSP + 1);
      float sw = 0.0f;
#pragma unroll
      for (int k2 = 0; k2 < KSP; ++k2) sw += rw[k2];
      s = sab[m] * s + sab[20 + m] * sw;
    }
    int ng = blockIdx.x * CT + cc;
    if constexpr (KV) {
      if (ng < D) {
        Cout[(size_t)m * Nd + ng] = s;
      } else if (ng < 2 * D) {
        cacheK[(((size_t)l * BN + m) * T + t) * D + (ng - D)] = s;
      } else {
        cacheV[(((size_t)l * BN + m) * T + t) * D + (ng - 2 * D)] = s;
      }
    } else {
      size_t off = (size_t)m * Nd + ng;
      if (EPI == 1) s = Xres[off] + s;
      if (EPI == 2) s = gelu_f(s);
      Cout[off] = s;
    }
  }
}

// ---------------------------------------------------------------- fused LN + qkv-GEMV + KV store + self-attn + head-slice proj

__global__ __launch_bounds__(256) void qkv_selfattn2(const float* __restrict__ xd,
                                                     const float* __restrict__ Wqkv,
                                                     const float* __restrict__ Wso,
                                                     float* __restrict__ cacheK,
                                                     float* __restrict__ cacheV,
                                                     float* __restrict__ part1,
                                                     int t, int l) {
  __shared__ __align__(16) float xrow[1024];
  __shared__ __align__(16) float qv[64], kt[64], vt[64], ov[64];
  __shared__ float sc[96];
  __shared__ float wred[8];
  __shared__ float sv[2];
  int tid = threadIdx.x;
  int h = blockIdx.x / BN, bn = blockIdx.x % BN;
  float rstd, bco;
  row_ln_stats(xd, bn, xrow, wred, rstd, bco, tid);
  __syncthreads();
  if (tid < 192) {
    int part = tid >> 6;
    int c = tid & 63;
    const float* Wp = Wqkv + (size_t)part * D + (size_t)h * 64 + c;
    float acc = 0.0f, accw = 0.0f;
    for (int k = 0; k < 1024; k += 8) {
      float wv[8];
#pragma unroll
      for (int u = 0; u < 8; ++u) wv[u] = Wp[(size_t)(k + u) * (3 * D)];
#pragma unroll
      for (int u = 0; u < 8; ++u) {
        acc = fmaf(xrow[k + u], wv[u], acc);
        accw += wv[u];
      }
    }
    float val = rstd * acc + bco * accw;
    if (part == 0) {
      qv[c] = val;
    } else if (part == 1) {
      kt[c] = val;
      cacheK[(((size_t)l * BN + bn) * T + t) * D + h * 64 + c] = val;
    } else {
      vt[c] = val;
      cacheV[(((size_t)l * BN + bn) * T + t) * D + h * 64 + c] = val;
    }
  }
  __syncthreads();
  int n = t + 1;
  if (tid < t) {
    const float* kr = cacheK + (((size_t)l * BN + bn) * T + tid) * D + h * 64;
    float dot = 0.0f;
#pragma unroll
    for (int d4 = 0; d4 < 16; ++d4) {
      float4 kk = *(const float4*)(kr + d4 * 4);
      float4 qq = *(const float4*)(qv + d4 * 4);
      dot += qq.x * kk.x + qq.y * kk.y + qq.z * kk.z + qq.w * kk.w;
    }
    sc[tid] = dot * 0.125f;
  } else if (tid == t) {
    float dot = 0.0f;
#pragma unroll
    for (int d4 = 0; d4 < 16; ++d4) {
      float4 kk = *(const float4*)(kt + d4 * 4);
      float4 qq = *(const float4*)(qv + d4 * 4);
      dot += qq.x * kk.x + qq.y * kk.y + qq.z * kk.z + qq.w * kk.w;
    }
    sc[t] = dot * 0.125f;
  }
  __syncthreads();
  if (tid == 0) {
    float mx = -INFINITY;
    for (int k = 0; k < n; ++k) mx = fmaxf(mx, sc[k]);
    sv[0] = mx;
  }
  __syncthreads();
  if (tid < n) sc[tid] = expf(sc[tid] - sv[0]);
  __syncthreads();
  if (tid == 0) {
    float s = 0.0f;
    for (int k = 0; k < n; ++k) s += sc[k];
    sv[1] = s;
  }
  __syncthreads();
  if (tid < n) sc[tid] = sc[tid] / sv[1];
  __syncthreads();
  if (tid < 64) {
    const float* vb = cacheV + ((size_t)l * BN + bn) * T * D + h * 64 + tid;
    float o = 0.0f;
    for (int k = 0; k < t; ++k) o = fmaf(sc[k], vb[(size_t)k * D], o);
    o = fmaf(sc[t], vt[tid], o);
    ov[tid] = o;
  }
  __syncthreads();
  {
    int c0 = tid * 4;
    const float* wbase = Wso + (size_t)(h * 64) * D + c0;
    float4 a = {0.0f, 0.0f, 0.0f, 0.0f};
    for (int j = 0; j < 64; ++j) {
      float oj = ov[j];
      float4 wr = *(const float4*)(wbase + (size_t)j * D);
      a.x = fmaf(oj, wr.x, a.x); a.y = fmaf(oj, wr.y, a.y);
      a.z = fmaf(oj, wr.z, a.z); a.w = fmaf(oj, wr.w, a.w);
    }
    *(float4*)(part1 + ((size_t)h * BN + bn) * D + c0) = a;
  }
}

// ---------------------------------------------------------------- fused residual-sum + LN + caQ-GEMV + cross-attn

__global__ __launch_bounds__(256) void caq_crossattn2(const float* __restrict__ xd,
                                                      const float* __restrict__ part1,
                                                      const float* __restrict__ Wcq,
                                                      const float* __restrict__ cKVl,
                                                      const int* __restrict__ mask,
                                                      float* __restrict__ y,
                                                      float* __restrict__ ad) {
  __shared__ __align__(16) float xrow[1024];
  __shared__ __align__(16) float qv[64];
  __shared__ float sc[512];
  __shared__ float red[256];
  __shared__ float qred[256], qredw[256];
  __shared__ float wred[8];
  __shared__ float sv[2];
  int tid = threadIdx.x;
  int h = blockIdx.x / BN, bn = blockIdx.x % BN;
  int b = bn / NS;
  int w = tid >> 6, lane = tid & 63;
  int c0 = tid * 4;
  float4 r = *(const float4*)(xd + (size_t)bn * D + c0);
  for (int hh = 0; hh < H; ++hh) {
    float4 p = *(const float4*)(part1 + ((size_t)hh * BN + bn) * D + c0);
    r.x += p.x; r.y += p.y; r.z += p.z; r.w += p.w;
  }
  *(float4*)(xrow + c0) = r;
  if (h == 0) *(float4*)(y + (size_t)bn * D + c0) = r;
  float s = r.x + r.y + r.z + r.w;
#pragma unroll
  for (int o = 32; o > 0; o >>= 1) s += __shfl_xor(s, o);
  if (lane == 0) wred[w] = s;
  __syncthreads();
  float mean = (wred[0] + wred[1] + wred[2] + wred[3]) * (1.0f / 1024.0f);
  float da = r.x - mean, db = r.y - mean, dc = r.z - mean, dd = r.w - mean;
  float s2 = da * da + db * db + dc * dc + dd * dd;
#pragma unroll
  for (int o = 32; o > 0; o >>= 1) s2 += __shfl_xor(s2, o);
  if (lane == 0) wred[4 + w] = s2;
  __syncthreads();
  float rstd = 1.0f / sqrtf((wred[4] + wred[5] + wred[6] + wred[7]) * (1.0f / 1024.0f) + 1e-5f);
  float bco = -mean * rstd;
  {
    int c = tid & 63, ks = tid >> 6;
    const float* Wp = Wcq + (size_t)(ks * 256) * D + (size_t)h * 64 + c;
    float acc = 0.0f, accw = 0.0f;
    for (int k = 0; k < 256; k += 8) {
      float wv[8];
#pragma unroll
      for (int u = 0; u < 8; ++u) wv[u] = Wp[(size_t)(k + u) * D];
#pragma unroll
      for (int u = 0; u < 8; ++u) {
        acc = fmaf(xrow[ks * 256 + k + u], wv[u], acc);
        accw += wv[u];
      }
    }
    qred[ks * 64 + c] = acc;
    qredw[ks * 64 + c] = accw;
  }
  __syncthreads();
  if (tid < 64) {
    float a = qred[tid] + qred[64 + tid] + qred[128 + tid] + qred[192 + tid];
    float aw = qredw[tid] + qredw[64 + tid] + qredw[128 + tid] + qredw[192 + tid];
    qv[tid] = rstd * a + bco * aw;
  }
  __syncthreads();
  const float* base = cKVl + (size_t)b * S * (2 * D);
  float lmax = -INFINITY;
  for (int s3 = tid; s3 < S; s3 += 256) {
    const float* kr = base + (size_t)s3 * (2 * D) + h * 64;
    float dot = 0.0f;
#pragma unroll
    for (int d4 = 0; d4 < 16; ++d4) {
      float4 kk = *(const float4*)(kr + d4 * 4);
      float4 qq = *(const float4*)(qv + d4 * 4);
      dot += qq.x * kk.x + qq.y * kk.y + qq.z * kk.z + qq.w * kk.w;
    }
    float bias = (1.0f - (float)mask[b * S + s3]) * -1e9f;
    float val = dot * 0.125f + bias;
    sc[s3] = val;
    lmax = fmaxf(lmax, val);
  }
  red[tid] = lmax; __syncthreads();
  for (int k = 128; k > 0; k >>= 1) { if (tid < k) red[tid] = fmaxf(red[tid], red[tid + k]); __syncthreads(); }
  if (tid == 0) sv[0] = red[0];
  __syncthreads();
  float mx = sv[0];
  float lsum = 0.0f;
  for (int s3 = tid; s3 < S; s3 += 256) { float e = expf(sc[s3] - mx); sc[s3] = e; lsum += e; }
  red[tid] = lsum; __syncthreads();
  for (int k = 128; k > 0; k >>= 1) { if (tid < k) red[tid] += red[tid + k]; __syncthreads(); }
  if (tid == 0) sv[1] = red[0];
  __syncthreads();
  float den = sv[1];
  for (int s3 = tid; s3 < S; s3 += 256) sc[s3] = sc[s3] / den;
  __syncthreads();
  int d = tid & 63, c = tid >> 6;
  const float* vb = base + D + h * 64 + d;
  float part = 0.0f;
  for (int s3 = c * 128; s3 < c * 128 + 128; ++s3)
    part = fmaf(sc[s3], vb[(size_t)s3 * (2 * D)], part);
  red[tid] = part; __syncthreads();
  if (tid < 64) {
    float o = red[tid] + red[tid + 64] + red[tid + 128] + red[tid + 192];
    ad[(size_t)bn * D + h * 64 + tid] = o;
  }
}

// ---------------------------------------------------------------- logits5 = LN(xd) @ E^T, K-split 2-way
// 256 thr = {khalf 0,1} x {128 cols}; waves uniform in khalf -> x reads are
// wave-uniform global loads (L2-hot, 80KB). No x LDS staging -> grid 751
// (~2.9 blocks/CU, ~11.7 active waves/CU, 2x the 1-thread-per-col cap).
// LN applied algebraically at the end; halves combined in fixed order.

__global__ __launch_bounds__(256) void logits5(const float* __restrict__ xd,
                                               const float* __restrict__ E,
                                               float* __restrict__ logits) {
  __shared__ float sab[40];
  __shared__ float reda[20][L5C];
  __shared__ float redw[L5C];
  int tid = threadIdx.x;
  {
    int w = tid >> 6, lane = tid & 63;
    for (int m = w; m < BN; m += 4) {
      const float* xr = xd + (size_t)m * D + lane * 16;
      float4 v[4];
      float sum = 0.0f;
#pragma unroll
      for (int j = 0; j < 4; ++j) {
        v[j] = *(const float4*)(xr + j * 4);
        sum += v[j].x + v[j].y + v[j].z + v[j].w;
      }
#pragma unroll
      for (int o = 32; o > 0; o >>= 1) sum += __shfl_xor(sum, o);
      float mean = sum * (1.0f / 1024.0f);
      float vs = 0.0f;
#pragma unroll
      for (int j = 0; j < 4; ++j) {
        float a = v[j].x - mean, b = v[j].y - mean, c2 = v[j].z - mean, d = v[j].w - mean;
        vs += a * a + b * b + c2 * c2 + d * d;
      }
#pragma unroll
      for (int o = 32; o > 0; o >>= 1) vs += __shfl_xor(vs, o);
      float rstd = 1.0f / sqrtf(vs * (1.0f / 1024.0f) + 1e-5f);
      if (lane == 0) { sab[m] = rstd; sab[20 + m] = -mean * rstd; }
    }
  }
  __syncthreads();
  int khalf = tid >> 7, col = tid & 127;
  int n = blockIdx.x * L5C + col;
  int nc = n < V ? n : V - 1;
  const float* er = E + (size_t)nc * D + khalf * 512;
  const float* xb = xd + khalf * 512;
  float acc[20] = {};
  float accw = 0.0f;
  for (int k = 0; k < 512; k += 8) {
    float4 e0 = *(const float4*)(er + k);
    float4 e1 = *(const float4*)(er + k + 4);
    accw += e0.x + e0.y + e0.z + e0.w + e1.x + e1.y + e1.z + e1.w;
#pragma unroll
    for (int m = 0; m < 20; ++m) {
      float4 x0 = *(const float4*)(xb + (size_t)m * D + k);
      float4 x1 = *(const float4*)(xb + (size_t)m * D + k + 4);
      float a = acc[m];
      a = fmaf(x0.x, e0.x, a); a = fmaf(x0.y, e0.y, a);
      a = fmaf(x0.z, e0.z, a); a = fmaf(x0.w, e0.w, a);
      a = fmaf(x1.x, e1.x, a); a = fmaf(x1.y, e1.y, a);
      a = fmaf(x1.z, e1.z, a); a = fmaf(x1.w, e1.w, a);
      acc[m] = a;
    }
  }
  if (khalf == 1) {
#pragma unroll
    for (int m = 0; m < 20; ++m) reda[m][col] = acc[m];
    redw[col] = accw;
  }
  __syncthreads();
  if (khalf == 0) {
    if (n < V) {
      float aw = accw + redw[col];
#pragma unroll
      for (int m = 0; m < 20; ++m) {
        float s = acc[m] + reda[m][col];
        logits[(size_t)m * VPAD + n] = sab[m] * s + sab[20 + m] * aw;
      }
    } else if (n == V) {
#pragma unroll
      for (int m = 0; m < 20; ++m)
        logits[(size_t)m * VPAD + V] = -1e30f;
    }
  }
}

// ---------------------------------------------------------------- top-k + gumbel sample + next embed

__global__ __launch_bounds__(256) void topk_sample(const float* __restrict__ logits,
                                                   int* __restrict__ toks,
                                                   const float* __restrict__ E,
                                                   const float* __restrict__ pos_d,
                                                   float* __restrict__ xd, int t) {
  __shared__ unsigned long long keys[2048];
  __shared__ float svals[128];
  __shared__ unsigned sidx[128];
  __shared__ int stok;
  int tid = threadIdx.x;
  int bn = blockIdx.x;
  const float* row = logits + (size_t)bn * VPAD;

  float tv[8]; unsigned ti[8];
#pragma unroll
  for (int j = 0; j < 8; ++j) { tv[j] = -INFINITY; ti[j] = 0xFFFFFFFFu; }

  for (int i4 = tid * 4; i4 < VPAD; i4 += 1024) {
    float4 v4 = *(const float4*)(row + i4);
    float vv[4] = {v4.x, v4.y, v4.z, v4.w};
#pragma unroll
    for (int j = 0; j < 4; ++j) {
      int i = i4 + j;
      float v = vv[j];
      if (t < 6 && i == EOS) v = -1e9f;
      if (v > tv[7]) {
        tv[7] = v; ti[7] = (unsigned)i;
#pragma unroll
        for (int jj = 7; jj > 0; --jj) {
          if (tv[jj] > tv[jj - 1]) {
            float a = tv[jj]; tv[jj] = tv[jj - 1]; tv[jj - 1] = a;
            unsigned bi = ti[jj]; ti[jj] = ti[jj - 1]; ti[jj - 1] = bi;
          }
        }
      }
    }
  }
#pragma unroll
  for (int j = 0; j < 8; ++j) keys[tid * 8 + j] = ~sort_key(tv[j], ti[j]);
  __syncthreads();

  for (int ksz = 2; ksz <= 2048; ksz <<= 1) {
    for (int jj = ksz >> 1; jj > 0; jj >>= 1) {
      for (int i = tid; i < 2048; i += 256) {
        int ixj = i ^ jj;
        if (ixj > i) {
          unsigned long long a = keys[i], b2 = keys[ixj];
          bool up = ((i & ksz) == 0);
          if ((a > b2) == up) { keys[i] = b2; keys[ixj] = a; }
        }
      }
      __syncthreads();
    }
  }

  if (tid < KTOP) {
    unsigned long long kk = ~keys[tid];
    unsigned sb = (unsigned)(kk >> 32);
    unsigned idx = 0xFFFFFFFFu - (unsigned)(kk & 0xFFFFFFFFull);
    unsigned fb = (sb & 0x80000000u) ? (sb ^ 0x80000000u) : ~sb;
    float v = __uint_as_float(fb);
    unsigned a0 = 0u, a1 = (unsigned)t;
    tf2x32(0u, 1234u, a0, a1);
    unsigned c0 = 0u, c1 = (unsigned)(bn * KTOP + tid);
    tf2x32(a0, a1, c0, c1);
    unsigned bits = c0 ^ c1;
    float f = __uint_as_float((bits >> 9) | 0x3f800000u) - 1.0f;
    float u = fmaxf(f, 1.17549435e-38f);
    float g = -logf(-logf(u));
    svals[tid] = v + g;
    sidx[tid] = idx;
  }
  __syncthreads();
  if (tid == 0) {
    int best = 0; float bv = svals[0];
    for (int j = 1; j < KTOP; ++j) { if (svals[j] > bv) { bv = svals[j]; best = j; } }
    int tok = (int)sidx[best];
    toks[bn * T + t] = tok;
    stok = tok;
  }
  __syncthreads();
  if (t + 1 < T) {
    int tok = stok;
    const float* er = E + (size_t)tok * D;
    const float* pr = pos_d + (size_t)(t + 1) * D;
    for (int j = tid; j < D; j += 256)
      xd[(size_t)bn * D + j] = er[j] * 32.0f + pr[j];
  }
}

// ---------------------------------------------------------------- host driver

extern "C" void kernel_launch(void* const* d_in, const int* in_sizes, int n_in,
                              void* d_out, int out_size, void* d_ws, size_t ws_size,
                              hipStream_t stream) {
  (void)in_sizes; (void)n_in; (void)out_size; (void)ws_size;

  const int*   ids   = (const int*)d_in[0];
  const int*   maskp = (const int*)d_in[1];
  const float* E     = (const float*)d_in[2];
  const float* pos_e = (const float*)d_in[3];
  const float* pos_d = (const float*)d_in[4];
  const float* eai   = (const float*)d_in[5];
  const float* eao   = (const float*)d_in[6];
  const float* ef1   = (const float*)d_in[7];
  const float* ef2   = (const float*)d_in[8];
  const float* dsi   = (const float*)d_in[9];
  const float* dso   = (const float*)d_in[10];
  const float* dcq   = (const float*)d_in[11];
  const float* dckv  = (const float*)d_in[12];
  const float* dco   = (const float*)d_in[13];
  const float* df1   = (const float*)d_in[14];
  const float* df2   = (const float*)d_in[15];

  float* ws = (float*)d_ws;
  size_t o = 0;
  auto alloc = [&](size_t n) { size_t r = o; o += (n + 63) & ~(size_t)63; return r; };
  float* cKV    = ws + alloc((size_t)NL * B * S * 2 * D);
  float* cacheK = ws + alloc((size_t)NL * BN * T * D);
  float* cacheV = ws + alloc((size_t)NL * BN * T * D);
  float* xe     = ws + alloc((size_t)B * S * D);
  float* he     = ws + alloc((size_t)B * S * D);
  float* qkvb   = ws + alloc((size_t)B * S * 3 * D);
  float* ab     = ws + alloc((size_t)B * S * D);
  float* ffb    = ws + alloc((size_t)B * S * F);
  // decoder scratch aliases the (then-idle) qkvb region
  float* xd      = qkvb;
  float* ad      = xd + BN * D;
  float* yb      = ad + BN * D;
  float* y2b     = yb + BN * D;
  float* ffd     = y2b + BN * D;
  float* part1   = ffd + BN * F;
  float* logitsb = part1 + H * BN * D;
  int* toks = (int*)d_out;

  // ---------------- encoder ----------------
  embed_enc<<<B * S, 256, 0, stream>>>(ids, E, pos_e, xe);
  for (int l = 0; l < NL; ++l) {
    ln_kernel<<<B * S, 256, 0, stream>>>(xe, he);
    gemm128<0><<<dim3(3 * D / 128, B * S / 128), 256, 0, stream>>>(
        he, eai + (size_t)l * D * 3 * D, nullptr, qkvb, D, 3 * D);
    enc_attn<<<B * H * S, 256, 0, stream>>>(qkvb, maskp, ab);
    gemm128<1><<<dim3(D / 128, B * S / 128), 256, 0, stream>>>(
        ab, eao + (size_t)l * D * D, xe, xe, D, D);
    ln_kernel<<<B * S, 256, 0, stream>>>(xe, he);
    gemm128<2><<<dim3(F / 128, B * S / 128), 256, 0, stream>>>(
        he, ef1 + (size_t)l * D * F, nullptr, ffb, D, F);
    gemm128<1><<<dim3(D / 128, B * S / 128), 256, 0, stream>>>(
        ffb, ef2 + (size_t)l * F * D, xe, xe, F, D);
  }
  ln_kernel<<<B * S, 256, 0, stream>>>(xe, he);
  for (int l = 0; l < NL; ++l) {
    gemm128<0><<<dim3(2 * D / 128, B * S / 128), 256, 0, stream>>>(
        he, dckv + (size_t)l * D * 2 * D, nullptr,
        cKV + (size_t)l * B * S * 2 * D, D, 2 * D);
  }

  // ---------------- decoder: 80 sequential sampling steps ----------------
  embed_dec<<<BN, 256, 0, stream>>>(E, pos_d, toks, xd, 0);
  for (int t = 0; t < T; ++t) {
    for (int l = 0; l < NL; ++l) {
      qkv_selfattn2<<<H * BN, 256, 0, stream>>>(
          xd, dsi + (size_t)l * D * 3 * D, dso + (size_t)l * D * D,
          cacheK, cacheV, part1, t, l);
      caq_crossattn2<<<H * BN, 256, 0, stream>>>(
          xd, part1, dcq + (size_t)l * D * D,
          cKV + (size_t)l * B * S * 2 * D, maskp, yb, ad);
      dec_gemm<8, 1, false, false><<<D / 8, 512, 0, stream>>>(
          ad, dco + (size_t)l * D * D, yb, y2b, nullptr, nullptr, D, D, 0, 0);
      dec_gemm<16, 2, false, true><<<F / 16, 512, 0, stream>>>(
          y2b, df1 + (size_t)l * D * F, nullptr, ffd, nullptr, nullptr, D, F, 0, 0);
      dec_gemm<8, 1, false, false><<<D / 8, 512, 0, stream>>>(
          ffd, df2 + (size_t)l * F * D, y2b, xd, nullptr, nullptr, F, D, 0, 0);
    }
    logits5<<<L5GRID, 256, 0, stream>>>(xd, E, logitsb);
    topk_sample<<<BN, 256, 0, stream>>>(logitsb, toks, E, pos_d, xd, t);
  }
}

// Round 12
// 53502.032 us; speedup vs baseline: 1.2810x; 1.2810x over previous
//
#include <hip/hip_runtime.h>
#include <cstdint>
#include <cstddef>

#define DEV __device__ __forceinline__

// Problem constants
constexpr int V  = 96103;
constexpr int VPAD = 96104;   // 16B-aligned logits row stride
constexpr int D  = 1024;
constexpr int H  = 16;
constexpr int DH = 64;
constexpr int F  = 4096;
constexpr int NL = 2;
constexpr int S  = 512;
constexpr int T  = 80;
constexpr int B  = 4;
constexpr int NS = 5;
constexpr int BN = 20;
constexpr int KTOP = 100;
constexpr int EOS = 1;
constexpr int LCOLS = 188;
constexpr int LGRID = (V + LCOLS - 1) / LCOLS;  // 512

// ---------------------------------------------------------------- utilities

DEV float gelu_f(float x) {
  float x3 = x * x * x;
  float inner = 0.7978845608028654f * (x + 0.044715f * x3);
  float tt = tanhf(inner);
  return x * (0.5f * (1.0f + tt));
}

DEV void tf2x32(unsigned k0, unsigned k1, unsigned& x0, unsigned& x1) {
  unsigned ks2 = k0 ^ k1 ^ 0x1BD11BDAu;
#define TFR(rr) { x0 += x1; x1 = (x1 << rr) | (x1 >> (32 - rr)); x1 ^= x0; }
  x0 += k0; x1 += k1;
  TFR(13) TFR(15) TFR(26) TFR(6)
  x0 += k1;  x1 += ks2 + 1u;
  TFR(17) TFR(29) TFR(16) TFR(24)
  x0 += ks2; x1 += k0 + 2u;
  TFR(13) TFR(15) TFR(26) TFR(6)
  x0 += k0;  x1 += k1 + 3u;
  TFR(17) TFR(29) TFR(16) TFR(24)
  x0 += k1;  x1 += ks2 + 4u;
  TFR(13) TFR(15) TFR(26) TFR(6)
  x0 += ks2; x1 += k0 + 5u;
#undef TFR
}

DEV unsigned long long sort_key(float v, unsigned idx) {
  unsigned bb = __float_as_uint(v);
  bb = (bb & 0x80000000u) ? ~bb : (bb | 0x80000000u);
  return ((unsigned long long)bb << 32) | (unsigned long long)(0xFFFFFFFFu - idx);
}

// wave-parallel LN of BN x 1024 rows into LDS xs[20][1024]
template<int NWAVE>
DEV void ln_to_lds(const float* __restrict__ x, float* xs, int tid) {
  int w = tid >> 6, lane = tid & 63;
  for (int m = w; m < BN; m += NWAVE) {
    float4 v[4];
    float sum = 0.0f;
#pragma unroll
    for (int j = 0; j < 4; ++j) {
      v[j] = *(const float4*)(x + m * D + j * 256 + lane * 4);
      sum += v[j].x + v[j].y + v[j].z + v[j].w;
    }
#pragma unroll
    for (int o = 32; o > 0; o >>= 1) sum += __shfl_xor(sum, o);
    float mean = sum * (1.0f / 1024.0f);
    float vs = 0.0f;
#pragma unroll
    for (int j = 0; j < 4; ++j) {
      float a = v[j].x - mean, b = v[j].y - mean, c = v[j].z - mean, d = v[j].w - mean;
      vs += a * a + b * b + c * c + d * d;
    }
#pragma unroll
    for (int o = 32; o > 0; o >>= 1) vs += __shfl_xor(vs, o);
    float rsig = 1.0f / sqrtf(vs * (1.0f / 1024.0f) + 1e-5f);
#pragma unroll
    for (int j = 0; j < 4; ++j) {
      float4 ov;
      ov.x = (v[j].x - mean) * rsig; ov.y = (v[j].y - mean) * rsig;
      ov.z = (v[j].z - mean) * rsig; ov.w = (v[j].w - mean) * rsig;
      *(float4*)(xs + m * D + j * 256 + lane * 4) = ov;
    }
  }
}

// stage one x-row into LDS + compute LN stats. 256 thr.
DEV void row_ln_stats(const float* __restrict__ xd, int bn, float* xrow,
                      float* wred, float& rstd, float& bco, int tid) {
  int w = tid >> 6, lane = tid & 63;
  float4 v = *(const float4*)(xd + (size_t)bn * D + w * 256 + lane * 4);
  *(float4*)(xrow + w * 256 + lane * 4) = v;
  float s = v.x + v.y + v.z + v.w;
#pragma unroll
  for (int o = 32; o > 0; o >>= 1) s += __shfl_xor(s, o);
  if (lane == 0) wred[w] = s;
  __syncthreads();
  float mean = (wred[0] + wred[1] + wred[2] + wred[3]) * (1.0f / 1024.0f);
  float a = v.x - mean, b = v.y - mean, c = v.z - mean, d = v.w - mean;
  float s2 = a * a + b * b + c * c + d * d;
#pragma unroll
  for (int o = 32; o > 0; o >>= 1) s2 += __shfl_xor(s2, o);
  if (lane == 0) wred[4 + w] = s2;
  __syncthreads();
  rstd = 1.0f / sqrtf((wred[4] + wred[5] + wred[6] + wred[7]) * (1.0f / 1024.0f) + 1e-5f);
  bco = -mean * rstd;
}

// ---------------------------------------------------------------- embeddings

__global__ __launch_bounds__(256) void embed_enc(const int* __restrict__ ids,
                                                 const float* __restrict__ E,
                                                 const float* __restrict__ pos_e,
                                                 float* __restrict__ xe) {
  int row = blockIdx.x;
  int id = ids[row];
  const float* er = E + (size_t)id * D;
  const float* pr = pos_e + (size_t)(row % S) * D;
  float* xr = xe + (size_t)row * D;
  for (int j = threadIdx.x; j < D; j += 256)
    xr[j] = er[j] * 32.0f + pr[j];
}

__global__ __launch_bounds__(256) void embed_dec(const float* __restrict__ E,
                                                 const float* __restrict__ pos_d,
                                                 const int* __restrict__ toks,
                                                 float* __restrict__ xd, int t) {
  int bn = blockIdx.x;
  int prev = (t == 0) ? 0 : toks[bn * T + (t - 1)];
  const float* er = E + (size_t)prev * D;
  const float* pr = pos_d + (size_t)t * D;
  float* xr = xd + (size_t)bn * D;
  for (int j = threadIdx.x; j < D; j += 256)
    xr[j] = er[j] * 32.0f + pr[j];
}

// ---------------------------------------------------------------- layernorm (encoder)

__global__ __launch_bounds__(256) void ln_kernel(const float* __restrict__ x,
                                                 float* __restrict__ y) {
  __shared__ float red[256];
  __shared__ float sv[2];
  int tid = threadIdx.x;
  const float* xr = x + (size_t)blockIdx.x * D;
  float4 v = *(const float4*)(xr + tid * 4);
  red[tid] = v.x + v.y + v.z + v.w;
  __syncthreads();
  for (int k = 128; k > 0; k >>= 1) { if (tid < k) red[tid] += red[tid + k]; __syncthreads(); }
  if (tid == 0) sv[0] = red[0] * (1.0f / 1024.0f);
  __syncthreads();
  float m = sv[0];
  float dx = v.x - m, dy = v.y - m, dz = v.z - m, dw = v.w - m;
  red[tid] = dx * dx + dy * dy + dz * dz + dw * dw;
  __syncthreads();
  for (int k = 128; k > 0; k >>= 1) { if (tid < k) red[tid] += red[tid + k]; __syncthreads(); }
  if (tid == 0) sv[1] = 1.0f / sqrtf(red[0] * (1.0f / 1024.0f) + 1e-5f);
  __syncthreads();
  float r = sv[1];
  float* yr = y + (size_t)blockIdx.x * D;
  float4 o; o.x = dx * r; o.y = dy * r; o.z = dz * r; o.w = dw * r;
  *(float4*)(yr + tid * 4) = o;
}

// ---------------------------------------------------------------- encoder GEMM 128x128

template<int EPI>
__global__ __launch_bounds__(256) void gemm128(const float* __restrict__ A,
                                               const float* __restrict__ W,
                                               const float* X, float* C,
                                               int Kd, int Nd) {
  __shared__ __align__(16) float As[8][128];
  __shared__ __align__(16) float Bs[8][128];
  int tid = threadIdx.x;
  int n0 = blockIdx.x * 128, m0 = blockIdx.y * 128;
  int tx = tid & 15, ty = tid >> 4;
  int ar = tid >> 1, ac = (tid & 1) * 4;
  int br = tid >> 5, bc = (tid & 31) * 4;
  float acc[8][8] = {};
  for (int k0 = 0; k0 < Kd; k0 += 8) {
    float4 av = *(const float4*)(A + (size_t)(m0 + ar) * Kd + k0 + ac);
    float4 wv = *(const float4*)(W + (size_t)(k0 + br) * Nd + n0 + bc);
    __syncthreads();
    As[ac + 0][ar] = av.x; As[ac + 1][ar] = av.y;
    As[ac + 2][ar] = av.z; As[ac + 3][ar] = av.w;
    *(float4*)&Bs[br][bc] = wv;
    __syncthreads();
#pragma unroll
    for (int k = 0; k < 8; ++k) {
      float a8[8], b8[8];
      *(float4*)&a8[0] = *(const float4*)&As[k][ty * 8];
      *(float4*)&a8[4] = *(const float4*)&As[k][ty * 8 + 4];
      *(float4*)&b8[0] = *(const float4*)&Bs[k][tx * 8];
      *(float4*)&b8[4] = *(const float4*)&Bs[k][tx * 8 + 4];
#pragma unroll
      for (int i = 0; i < 8; ++i)
#pragma unroll
        for (int j = 0; j < 8; ++j)
          acc[i][j] = fmaf(a8[i], b8[j], acc[i][j]);
    }
  }
#pragma unroll
  for (int i = 0; i < 8; ++i) {
    int m = m0 + ty * 8 + i;
#pragma unroll
    for (int j = 0; j < 8; ++j) {
      int n = n0 + tx * 8 + j;
      float r = acc[i][j];
      size_t off = (size_t)m * Nd + n;
      if (EPI == 1) r = X[off] + r;
      if (EPI == 2) r = gelu_f(r);
      C[off] = r;
    }
  }
}

// ---------------------------------------------------------------- encoder attention

__global__ __launch_bounds__(256) void enc_attn(const float* __restrict__ qkv,
                                                const int* __restrict__ mask,
                                                float* __restrict__ ab) {
  __shared__ __align__(16) float qv[64];
  __shared__ float sc[512];
  __shared__ float red[256];
  __shared__ float sv[2];
  int tid = threadIdx.x;
  int q = blockIdx.x % S;
  int h = (blockIdx.x / S) % H;
  int b = blockIdx.x / (S * H);
  const float* qrow = qkv + (size_t)(b * S + q) * (3 * D) + h * 64;
  if (tid < 64) qv[tid] = qrow[tid];
  __syncthreads();
  float lmax = -INFINITY;
  for (int k = tid; k < S; k += 256) {
    const float* kr = qkv + (size_t)(b * S + k) * (3 * D) + D + h * 64;
    float dot = 0.0f;
#pragma unroll
    for (int d4 = 0; d4 < 16; ++d4) {
      float4 kk = *(const float4*)(kr + d4 * 4);
      float4 qq = *(const float4*)(qv + d4 * 4);
      dot += qq.x * kk.x + qq.y * kk.y + qq.z * kk.z + qq.w * kk.w;
    }
    float bias = (1.0f - (float)mask[b * S + k]) * -1e9f;
    float val = dot * 0.125f + bias;
    sc[k] = val;
    lmax = fmaxf(lmax, val);
  }
  red[tid] = lmax; __syncthreads();
  for (int k = 128; k > 0; k >>= 1) { if (tid < k) red[tid] = fmaxf(red[tid], red[tid + k]); __syncthreads(); }
  if (tid == 0) sv[0] = red[0];
  __syncthreads();
  float mx = sv[0];
  float lsum = 0.0f;
  for (int k = tid; k < S; k += 256) { float e = expf(sc[k] - mx); sc[k] = e; lsum += e; }
  red[tid] = lsum; __syncthreads();
  for (int k = 128; k > 0; k >>= 1) { if (tid < k) red[tid] += red[tid + k]; __syncthreads(); }
  if (tid == 0) sv[1] = red[0];
  __syncthreads();
  float den = sv[1];
  for (int k = tid; k < S; k += 256) sc[k] = sc[k] / den;
  __syncthreads();
  int d = tid & 63, c = tid >> 6;
  const float* vb = qkv + (size_t)(b * S) * (3 * D) + 2 * D + h * 64 + d;
  float part = 0.0f;
  for (int k = c * 128; k < c * 128 + 128; ++k)
    part = fmaf(sc[k], vb[(size_t)k * (3 * D)], part);
  red[tid] = part; __syncthreads();
  if (tid < 64) {
    float o = red[tid] + red[tid + 64] + red[tid + 128] + red[tid + 192];
    ab[(size_t)(b * S + q) * D + h * 64 + tid] = o;
  }
}

// ---------------------------------------------------------------- fused decode GEMM (r3-proven)

template<int CT, int EPI, bool KV, bool LNIN>
__global__ __launch_bounds__(512) void dec_gemm(const float* __restrict__ x,
                                                const float* __restrict__ W,
                                                const float* Xres, float* Cout,
                                                float* __restrict__ cacheK,
                                                float* __restrict__ cacheV,
                                                int Kd, int Nd, int t, int l) {
  constexpr int KSP = 512 / CT;
  __shared__ float red[CT * 20 * (KSP + 1)];
  __shared__ float redw[CT * (KSP + 1)];
  __shared__ float sab[40];
  int tid = threadIdx.x;
  if constexpr (LNIN) {
    int w = tid >> 6, lane = tid & 63;
    for (int m = w; m < BN; m += 8) {
      const float* xr = x + (size_t)m * 1024 + lane * 16;
      float4 v[4];
      float sum = 0.0f;
#pragma unroll
      for (int j = 0; j < 4; ++j) {
        v[j] = *(const float4*)(xr + j * 4);
        sum += v[j].x + v[j].y + v[j].z + v[j].w;
      }
#pragma unroll
      for (int o = 32; o > 0; o >>= 1) sum += __shfl_xor(sum, o);
      float mean = sum * (1.0f / 1024.0f);
      float vs = 0.0f;
#pragma unroll
      for (int j = 0; j < 4; ++j) {
        float a = v[j].x - mean, b = v[j].y - mean, c2 = v[j].z - mean, d = v[j].w - mean;
        vs += a * a + b * b + c2 * c2 + d * d;
      }
#pragma unroll
      for (int o = 32; o > 0; o >>= 1) vs += __shfl_xor(vs, o);
      float rstd = 1.0f / sqrtf(vs * (1.0f / 1024.0f) + 1e-5f);
      if (lane == 0) { sab[m] = rstd; sab[20 + m] = -mean * rstd; }
    }
    __syncthreads();
  }
  int c = tid % CT, ks = tid / CT;
  int klen = Kd / KSP;
  const float* Wp = W + (size_t)(ks * klen) * Nd + blockIdx.x * CT + c;
  float acc[20] = {};
  float accw = 0.0f;
  for (int kk = 0; kk < klen; kk += 8) {
    float wv[8];
#pragma unroll
    for (int u = 0; u < 8; ++u) wv[u] = Wp[(size_t)u * Nd];
    Wp += (size_t)8 * Nd;
    if constexpr (LNIN)
      accw += wv[0] + wv[1] + wv[2] + wv[3] + wv[4] + wv[5] + wv[6] + wv[7];
    int kb = ks * klen + kk;
#pragma unroll
    for (int m = 0; m < 20; ++m) {
      float4 x0 = *(const float4*)(x + (size_t)m * Kd + kb);
      float4 x1 = *(const float4*)(x + (size_t)m * Kd + kb + 4);
      float a = acc[m];
      a = fmaf(x0.x, wv[0], a); a = fmaf(x0.y, wv[1], a);
      a = fmaf(x0.z, wv[2], a); a = fmaf(x0.w, wv[3], a);
      a = fmaf(x1.x, wv[4], a); a = fmaf(x1.y, wv[5], a);
      a = fmaf(x1.z, wv[6], a); a = fmaf(x1.w, wv[7], a);
      acc[m] = a;
    }
  }
#pragma unroll
  for (int m = 0; m < 20; ++m) red[(c * 20 + m) * (KSP + 1) + ks] = acc[m];
  if constexpr (LNIN) redw[c * (KSP + 1) + ks] = accw;
  __syncthreads();
  if (tid < CT * 20) {
    int cc = tid % CT, m = tid / CT;
    const float* rp = red + (cc * 20 + m) * (KSP + 1);
    float s = 0.0f;
#pragma unroll
    for (int k2 = 0; k2 < KSP; ++k2) s += rp[k2];
    if constexpr (LNIN) {
      const float* rw = redw + cc * (KSP + 1);
      float sw = 0.0f;
#pragma unroll
      for (int k2 = 0; k2 < KSP; ++k2) sw += rw[k2];
      s = sab[m] * s + sab[20 + m] * sw;
    }
    int ng = blockIdx.x * CT + cc;
    if constexpr (KV) {
      if (ng < D) {
        Cout[(size_t)m * Nd + ng] = s;
      } else if (ng < 2 * D) {
        cacheK[(((size_t)l * BN + m) * T + t) * D + (ng - D)] = s;
      } else {
        cacheV[(((size_t)l * BN + m) * T + t) * D + (ng - 2 * D)] = s;
      }
    } else {
      size_t off = (size_t)m * Nd + ng;
      if (EPI == 1) s = Xres[off] + s;
      if (EPI == 2) s = gelu_f(s);
      Cout[off] = s;
    }
  }
}

// ---------------------------------------------------------------- fused LN + qkv-GEMV + KV store + self-attn + head-slice proj

__global__ __launch_bounds__(256) void qkv_selfattn2(const float* __restrict__ xd,
                                                     const float* __restrict__ Wqkv,
                                                     const float* __restrict__ Wso,
                                                     float* __restrict__ cacheK,
                                                     float* __restrict__ cacheV,
                                                     float* __restrict__ part1,
                                                     int t, int l) {
  __shared__ __align__(16) float xrow[1024];
  __shared__ __align__(16) float qv[64], kt[64], vt[64], ov[64];
  __shared__ float sc[96];
  __shared__ float wred[8];
  __shared__ float sv[2];
  int tid = threadIdx.x;
  int h = blockIdx.x / BN, bn = blockIdx.x % BN;
  float rstd, bco;
  row_ln_stats(xd, bn, xrow, wred, rstd, bco, tid);
  __syncthreads();
  if (tid < 192) {
    int part = tid >> 6;
    int c = tid & 63;
    const float* Wp = Wqkv + (size_t)part * D + (size_t)h * 64 + c;
    float acc = 0.0f, accw = 0.0f;
    for (int k = 0; k < 1024; k += 8) {
      float wv[8];
#pragma unroll
      for (int u = 0; u < 8; ++u) wv[u] = Wp[(size_t)(k + u) * (3 * D)];
#pragma unroll
      for (int u = 0; u < 8; ++u) {
        acc = fmaf(xrow[k + u], wv[u], acc);
        accw += wv[u];
      }
    }
    float val = rstd * acc + bco * accw;
    if (part == 0) {
      qv[c] = val;
    } else if (part == 1) {
      kt[c] = val;
      cacheK[(((size_t)l * BN + bn) * T + t) * D + h * 64 + c] = val;
    } else {
      vt[c] = val;
      cacheV[(((size_t)l * BN + bn) * T + t) * D + h * 64 + c] = val;
    }
  }
  __syncthreads();
  int n = t + 1;
  if (tid < t) {
    const float* kr = cacheK + (((size_t)l * BN + bn) * T + tid) * D + h * 64;
    float dot = 0.0f;
#pragma unroll
    for (int d4 = 0; d4 < 16; ++d4) {
      float4 kk = *(const float4*)(kr + d4 * 4);
      float4 qq = *(const float4*)(qv + d4 * 4);
      dot += qq.x * kk.x + qq.y * kk.y + qq.z * kk.z + qq.w * kk.w;
    }
    sc[tid] = dot * 0.125f;
  } else if (tid == t) {
    float dot = 0.0f;
#pragma unroll
    for (int d4 = 0; d4 < 16; ++d4) {
      float4 kk = *(const float4*)(kt + d4 * 4);
      float4 qq = *(const float4*)(qv + d4 * 4);
      dot += qq.x * kk.x + qq.y * kk.y + qq.z * kk.z + qq.w * kk.w;
    }
    sc[t] = dot * 0.125f;
  }
  __syncthreads();
  if (tid == 0) {
    float mx = -INFINITY;
    for (int k = 0; k < n; ++k) mx = fmaxf(mx, sc[k]);
    sv[0] = mx;
  }
  __syncthreads();
  if (tid < n) sc[tid] = expf(sc[tid] - sv[0]);
  __syncthreads();
  if (tid == 0) {
    float s = 0.0f;
    for (int k = 0; k < n; ++k) s += sc[k];
    sv[1] = s;
  }
  __syncthreads();
  if (tid < n) sc[tid] = sc[tid] / sv[1];
  __syncthreads();
  if (tid < 64) {
    const float* vb = cacheV + ((size_t)l * BN + bn) * T * D + h * 64 + tid;
    float o = 0.0f;
    for (int k = 0; k < t; ++k) o = fmaf(sc[k], vb[(size_t)k * D], o);
    o = fmaf(sc[t], vt[tid], o);
    ov[tid] = o;
  }
  __syncthreads();
  {
    int c0 = tid * 4;
    const float* wbase = Wso + (size_t)(h * 64) * D + c0;
    float4 a = {0.0f, 0.0f, 0.0f, 0.0f};
    for (int j = 0; j < 64; ++j) {
      float oj = ov[j];
      float4 wr = *(const float4*)(wbase + (size_t)j * D);
      a.x = fmaf(oj, wr.x, a.x); a.y = fmaf(oj, wr.y, a.y);
      a.z = fmaf(oj, wr.z, a.z); a.w = fmaf(oj, wr.w, a.w);
    }
    *(float4*)(part1 + ((size_t)h * BN + bn) * D + c0) = a;
  }
}

// ---------------------------------------------------------------- fused residual-sum + LN + caQ-GEMV + cross-attn + head-slice proj
// r = xd[bn] + sum_h part1[h][bn]; h==0 writes r -> y; emits part2[h][bn][:] = o_h @ Wco[h*64..,:]

__global__ __launch_bounds__(256) void caq_crossattn3(const float* __restrict__ xd,
                                                      const float* __restrict__ part1,
                                                      const float* __restrict__ Wcq,
                                                      const float* __restrict__ Wco,
                                                      const float* __restrict__ cKVl,
                                                      const int* __restrict__ mask,
                                                      float* __restrict__ y,
                                                      float* __restrict__ part2) {
  __shared__ __align__(16) float xrow[1024];
  __shared__ __align__(16) float qv[64], ov[64];
  __shared__ float sc[512];
  __shared__ float red[256];
  __shared__ float qred[256], qredw[256];
  __shared__ float wred[8];
  __shared__ float sv[2];
  int tid = threadIdx.x;
  int h = blockIdx.x / BN, bn = blockIdx.x % BN;
  int b = bn / NS;
  int w = tid >> 6, lane = tid & 63;
  int c0 = tid * 4;
  float4 r = *(const float4*)(xd + (size_t)bn * D + c0);
  for (int hh = 0; hh < H; ++hh) {
    float4 p = *(const float4*)(part1 + ((size_t)hh * BN + bn) * D + c0);
    r.x += p.x; r.y += p.y; r.z += p.z; r.w += p.w;
  }
  *(float4*)(xrow + c0) = r;
  if (h == 0) *(float4*)(y + (size_t)bn * D + c0) = r;
  float s = r.x + r.y + r.z + r.w;
#pragma unroll
  for (int o = 32; o > 0; o >>= 1) s += __shfl_xor(s, o);
  if (lane == 0) wred[w] = s;
  __syncthreads();
  float mean = (wred[0] + wred[1] + wred[2] + wred[3]) * (1.0f / 1024.0f);
  float da = r.x - mean, db = r.y - mean, dc = r.z - mean, dd = r.w - mean;
  float s2 = da * da + db * db + dc * dc + dd * dd;
#pragma unroll
  for (int o = 32; o > 0; o >>= 1) s2 += __shfl_xor(s2, o);
  if (lane == 0) wred[4 + w] = s2;
  __syncthreads();
  float rstd = 1.0f / sqrtf((wred[4] + wred[5] + wred[6] + wred[7]) * (1.0f / 1024.0f) + 1e-5f);
  float bco = -mean * rstd;
  {
    int c = tid & 63, ks = tid >> 6;
    const float* Wp = Wcq + (size_t)(ks * 256) * D + (size_t)h * 64 + c;
    float acc = 0.0f, accw = 0.0f;
    for (int k = 0; k < 256; k += 8) {
      float wv[8];
#pragma unroll
      for (int u = 0; u < 8; ++u) wv[u] = Wp[(size_t)(k + u) * D];
#pragma unroll
      for (int u = 0; u < 8; ++u) {
        acc = fmaf(xrow[ks * 256 + k + u], wv[u], acc);
        accw += wv[u];
      }
    }
    qred[ks * 64 + c] = acc;
    qredw[ks * 64 + c] = accw;
  }
  __syncthreads();
  if (tid < 64) {
    float a = qred[tid] + qred[64 + tid] + qred[128 + tid] + qred[192 + tid];
    float aw = qredw[tid] + qredw[64 + tid] + qredw[128 + tid] + qredw[192 + tid];
    qv[tid] = rstd * a + bco * aw;
  }
  __syncthreads();
  const float* base = cKVl + (size_t)b * S * (2 * D);
  float lmax = -INFINITY;
  for (int s3 = tid; s3 < S; s3 += 256) {
    const float* kr = base + (size_t)s3 * (2 * D) + h * 64;
    float dot = 0.0f;
#pragma unroll
    for (int d4 = 0; d4 < 16; ++d4) {
      float4 kk = *(const float4*)(kr + d4 * 4);
      float4 qq = *(const float4*)(qv + d4 * 4);
      dot += qq.x * kk.x + qq.y * kk.y + qq.z * kk.z + qq.w * kk.w;
    }
    float bias = (1.0f - (float)mask[b * S + s3]) * -1e9f;
    float val = dot * 0.125f + bias;
    sc[s3] = val;
    lmax = fmaxf(lmax, val);
  }
  red[tid] = lmax; __syncthreads();
  for (int k = 128; k > 0; k >>= 1) { if (tid < k) red[tid] = fmaxf(red[tid], red[tid + k]); __syncthreads(); }
  if (tid == 0) sv[0] = red[0];
  __syncthreads();
  float mx = sv[0];
  float lsum = 0.0f;
  for (int s3 = tid; s3 < S; s3 += 256) { float e = expf(sc[s3] - mx); sc[s3] = e; lsum += e; }
  red[tid] = lsum; __syncthreads();
  for (int k = 128; k > 0; k >>= 1) { if (tid < k) red[tid] += red[tid + k]; __syncthreads(); }
  if (tid == 0) sv[1] = red[0];
  __syncthreads();
  float den = sv[1];
  for (int s3 = tid; s3 < S; s3 += 256) sc[s3] = sc[s3] / den;
  __syncthreads();
  int d = tid & 63, c = tid >> 6;
  const float* vb = base + D + h * 64 + d;
  float part = 0.0f;
  for (int s3 = c * 128; s3 < c * 128 + 128; ++s3)
    part = fmaf(sc[s3], vb[(size_t)s3 * (2 * D)], part);
  red[tid] = part; __syncthreads();
  if (tid < 64) {
    float o = red[tid] + red[tid + 64] + red[tid + 128] + red[tid + 192];
    ov[tid] = o;
  }
  __syncthreads();
  // head-slice projection through Wco
  {
    const float* wbase = Wco + (size_t)(h * 64) * D + c0;
    float4 a = {0.0f, 0.0f, 0.0f, 0.0f};
    for (int j = 0; j < 64; ++j) {
      float oj = ov[j];
      float4 wr = *(const float4*)(wbase + (size_t)j * D);
      a.x = fmaf(oj, wr.x, a.x); a.y = fmaf(oj, wr.y, a.y);
      a.z = fmaf(oj, wr.z, a.z); a.w = fmaf(oj, wr.w, a.w);
    }
    *(float4*)(part2 + ((size_t)h * BN + bn) * D + c0) = a;
  }
}

// ---------------------------------------------------------------- residual2: y2 = y + sum_h part2[h]

__global__ __launch_bounds__(256) void residual2(const float* __restrict__ yb,
                                                 const float* __restrict__ part2,
                                                 float* __restrict__ y2b) {
  int bn = blockIdx.x;
  int c0 = threadIdx.x * 4;
  float4 r = *(const float4*)(yb + (size_t)bn * D + c0);
  for (int hh = 0; hh < H; ++hh) {
    float4 p = *(const float4*)(part2 + ((size_t)hh * BN + bn) * D + c0);
    r.x += p.x; r.y += p.y; r.z += p.z; r.w += p.w;
  }
  *(float4*)(y2b + (size_t)bn * D + c0) = r;
}

// ---------------------------------------------------------------- logits3 = LN(xd) @ E^T (r6-proven)

__global__ __launch_bounds__(256) void logits3(const float* __restrict__ xd,
                                               const float* __restrict__ E,
                                               float* __restrict__ logits) {
  __shared__ float xs[20 * 1024];
  int tid = threadIdx.x;
  ln_to_lds<4>(xd, xs, tid);
  __syncthreads();
  int n = blockIdx.x * LCOLS + tid;
  if (tid < LCOLS && n < V) {
    const float* er = E + (size_t)n * D;
    float acc[20] = {};
    for (int k = 0; k < 1024; k += 8) {
      float4 e0 = *(const float4*)(er + k);
      float4 e1 = *(const float4*)(er + k + 4);
#pragma unroll
      for (int m = 0; m < 20; ++m) {
        const float* xb = xs + m * 1024 + k;
        float4 x0 = *(const float4*)(xb);
        float4 x1 = *(const float4*)(xb + 4);
        float a = acc[m];
        a = fmaf(x0.x, e0.x, a); a = fmaf(x0.y, e0.y, a);
        a = fmaf(x0.z, e0.z, a); a = fmaf(x0.w, e0.w, a);
        a = fmaf(x1.x, e1.x, a); a = fmaf(x1.y, e1.y, a);
        a = fmaf(x1.z, e1.z, a); a = fmaf(x1.w, e1.w, a);
        acc[m] = a;
      }
    }
#pragma unroll
    for (int m = 0; m < 20; ++m)
      logits[(size_t)m * VPAD + n] = acc[m];
  } else if (n == V) {
#pragma unroll
    for (int m = 0; m < 20; ++m)
      logits[(size_t)m * VPAD + V] = -1e30f;
  }
}

// ---------------------------------------------------------------- top-k + gumbel sample + next embed

__global__ __launch_bounds__(256) void topk_sample(const float* __restrict__ logits,
                                                   int* __restrict__ toks,
                                                   const float* __restrict__ E,
                                                   const float* __restrict__ pos_d,
                                                   float* __restrict__ xd, int t) {
  __shared__ unsigned long long keys[2048];
  __shared__ float svals[128];
  __shared__ unsigned sidx[128];
  __shared__ int stok;
  int tid = threadIdx.x;
  int bn = blockIdx.x;
  const float* row = logits + (size_t)bn * VPAD;

  float tv[8]; unsigned ti[8];
#pragma unroll
  for (int j = 0; j < 8; ++j) { tv[j] = -INFINITY; ti[j] = 0xFFFFFFFFu; }

  for (int i4 = tid * 4; i4 < VPAD; i4 += 1024) {
    float4 v4 = *(const float4*)(row + i4);
    float vv[4] = {v4.x, v4.y, v4.z, v4.w};
#pragma unroll
    for (int j = 0; j < 4; ++j) {
      int i = i4 + j;
      float v = vv[j];
      if (t < 6 && i == EOS) v = -1e9f;
      if (v > tv[7]) {
        tv[7] = v; ti[7] = (unsigned)i;
#pragma unroll
        for (int jj = 7; jj > 0; --jj) {
          if (tv[jj] > tv[jj - 1]) {
            float a = tv[jj]; tv[jj] = tv[jj - 1]; tv[jj - 1] = a;
            unsigned bi = ti[jj]; ti[jj] = ti[jj - 1]; ti[jj - 1] = bi;
          }
        }
      }
    }
  }
#pragma unroll
  for (int j = 0; j < 8; ++j) keys[tid * 8 + j] = ~sort_key(tv[j], ti[j]);
  __syncthreads();

  for (int ksz = 2; ksz <= 2048; ksz <<= 1) {
    for (int jj = ksz >> 1; jj > 0; jj >>= 1) {
      for (int i = tid; i < 2048; i += 256) {
        int ixj = i ^ jj;
        if (ixj > i) {
          unsigned long long a = keys[i], b2 = keys[ixj];
          bool up = ((i & ksz) == 0);
          if ((a > b2) == up) { keys[i] = b2; keys[ixj] = a; }
        }
      }
      __syncthreads();
    }
  }

  if (tid < KTOP) {
    unsigned long long kk = ~keys[tid];
    unsigned sb = (unsigned)(kk >> 32);
    unsigned idx = 0xFFFFFFFFu - (unsigned)(kk & 0xFFFFFFFFull);
    unsigned fb = (sb & 0x80000000u) ? (sb ^ 0x80000000u) : ~sb;
    float v = __uint_as_float(fb);
    unsigned a0 = 0u, a1 = (unsigned)t;
    tf2x32(0u, 1234u, a0, a1);
    unsigned c0 = 0u, c1 = (unsigned)(bn * KTOP + tid);
    tf2x32(a0, a1, c0, c1);
    unsigned bits = c0 ^ c1;
    float f = __uint_as_float((bits >> 9) | 0x3f800000u) - 1.0f;
    float u = fmaxf(f, 1.17549435e-38f);
    float g = -logf(-logf(u));
    svals[tid] = v + g;
    sidx[tid] = idx;
  }
  __syncthreads();
  if (tid == 0) {
    int best = 0; float bv = svals[0];
    for (int j = 1; j < KTOP; ++j) { if (svals[j] > bv) { bv = svals[j]; best = j; } }
    int tok = (int)sidx[best];
    toks[bn * T + t] = tok;
    stok = tok;
  }
  __syncthreads();
  if (t + 1 < T) {
    int tok = stok;
    const float* er = E + (size_t)tok * D;
    const float* pr = pos_d + (size_t)(t + 1) * D;
    for (int j = tid; j < D; j += 256)
      xd[(size_t)bn * D + j] = er[j] * 32.0f + pr[j];
  }
}

// ---------------------------------------------------------------- host driver

extern "C" void kernel_launch(void* const* d_in, const int* in_sizes, int n_in,
                              void* d_out, int out_size, void* d_ws, size_t ws_size,
                              hipStream_t stream) {
  (void)in_sizes; (void)n_in; (void)out_size; (void)ws_size;

  const int*   ids   = (const int*)d_in[0];
  const int*   maskp = (const int*)d_in[1];
  const float* E     = (const float*)d_in[2];
  const float* pos_e = (const float*)d_in[3];
  const float* pos_d = (const float*)d_in[4];
  const float* eai   = (const float*)d_in[5];
  const float* eao   = (const float*)d_in[6];
  const float* ef1   = (const float*)d_in[7];
  const float* ef2   = (const float*)d_in[8];
  const float* dsi   = (const float*)d_in[9];
  const float* dso   = (const float*)d_in[10];
  const float* dcq   = (const float*)d_in[11];
  const float* dckv  = (const float*)d_in[12];
  const float* dco   = (const float*)d_in[13];
  const float* df1   = (const float*)d_in[14];
  const float* df2   = (const float*)d_in[15];

  float* ws = (float*)d_ws;
  size_t o = 0;
  auto alloc = [&](size_t n) { size_t r = o; o += (n + 63) & ~(size_t)63; return r; };
  float* cKV    = ws + alloc((size_t)NL * B * S * 2 * D);
  float* cacheK = ws + alloc((size_t)NL * BN * T * D);
  float* cacheV = ws + alloc((size_t)NL * BN * T * D);
  float* xe     = ws + alloc((size_t)B * S * D);
  float* he     = ws + alloc((size_t)B * S * D);
  float* qkvb   = ws + alloc((size_t)B * S * 3 * D);
  float* ab     = ws + alloc((size_t)B * S * D);
  float* ffb    = ws + alloc((size_t)B * S * F);
  // decoder scratch aliases the (then-idle) qkvb region
  float* xd      = qkvb;
  float* yb      = xd + BN * D;
  float* y2b     = yb + BN * D;
  float* ffd     = y2b + BN * D;
  float* part1   = ffd + BN * F;
  float* part2   = part1 + H * BN * D;
  float* logitsb = part2 + H * BN * D;
  int* toks = (int*)d_out;

  // ---------------- encoder ----------------
  embed_enc<<<B * S, 256, 0, stream>>>(ids, E, pos_e, xe);
  for (int l = 0; l < NL; ++l) {
    ln_kernel<<<B * S, 256, 0, stream>>>(xe, he);
    gemm128<0><<<dim3(3 * D / 128, B * S / 128), 256, 0, stream>>>(
        he, eai + (size_t)l * D * 3 * D, nullptr, qkvb, D, 3 * D);
    enc_attn<<<B * H * S, 256, 0, stream>>>(qkvb, maskp, ab);
    gemm128<1><<<dim3(D / 128, B * S / 128), 256, 0, stream>>>(
        ab, eao + (size_t)l * D * D, xe, xe, D, D);
    ln_kernel<<<B * S, 256, 0, stream>>>(xe, he);
    gemm128<2><<<dim3(F / 128, B * S / 128), 256, 0, stream>>>(
        he, ef1 + (size_t)l * D * F, nullptr, ffb, D, F);
    gemm128<1><<<dim3(D / 128, B * S / 128), 256, 0, stream>>>(
        ffb, ef2 + (size_t)l * F * D, xe, xe, F, D);
  }
  ln_kernel<<<B * S, 256, 0, stream>>>(xe, he);
  for (int l = 0; l < NL; ++l) {
    gemm128<0><<<dim3(2 * D / 128, B * S / 128), 256, 0, stream>>>(
        he, dckv + (size_t)l * D * 2 * D, nullptr,
        cKV + (size_t)l * B * S * 2 * D, D, 2 * D);
  }

  // ---------------- decoder: 80 sequential sampling steps ----------------
  embed_dec<<<BN, 256, 0, stream>>>(E, pos_d, toks, xd, 0);
  for (int t = 0; t < T; ++t) {
    for (int l = 0; l < NL; ++l) {
      qkv_selfattn2<<<H * BN, 256, 0, stream>>>(
          xd, dsi + (size_t)l * D * 3 * D, dso + (size_t)l * D * D,
          cacheK, cacheV, part1, t, l);
      caq_crossattn3<<<H * BN, 256, 0, stream>>>(
          xd, part1, dcq + (size_t)l * D * D, dco + (size_t)l * D * D,
          cKV + (size_t)l * B * S * 2 * D, maskp, yb, part2);
      residual2<<<BN, 256, 0, stream>>>(yb, part2, y2b);
      dec_gemm<16, 2, false, true><<<F / 16, 512, 0, stream>>>(
          y2b, df1 + (size_t)l * D * F, nullptr, ffd, nullptr, nullptr, D, F, 0, 0);
      dec_gemm<8, 1, false, false><<<D / 8, 512, 0, stream>>>(
          ffd, df2 + (size_t)l * F * D, y2b, xd, nullptr, nullptr, F, D, 0, 0);
    }
    logits3<<<LGRID, 256, 0, stream>>>(xd, E, logitsb);
    topk_sample<<<BN, 256, 0, stream>>>(logitsb, toks, E, pos_d, xd, t);
  }
}